// Round 1
// baseline (1846.921 us; speedup 1.0000x reference)
//
#include <hip/hip_runtime.h>

// LSTM: B=2048, T=4096, I=5, H=10. fp32.
// One wave (64 lanes) per batch chain. Lane g<40 owns gate row g.
// Lanes 0..9 own h[j], c[j]. Gate order i,f,g,o (rows 0-9,10-19,20-29,30-39).

#define BB 2048
#define TT 4096
#define II 5
#define HH 10
#define GG 40

__global__ __launch_bounds__(64) void lstm_wave_kernel(
    const float* __restrict__ x,
    const float* __restrict__ h0,
    const float* __restrict__ c0,
    const float* __restrict__ W_ih,
    const float* __restrict__ W_hh,
    const float* __restrict__ b_ih,
    const float* __restrict__ b_hh,
    float* __restrict__ out)
{
    const int b = blockIdx.x;
    const int lane = threadIdx.x;
    const int g = lane;

    // Per-lane gate-row weights
    float wih[II];
    float whh[HH];
    float bias = 0.f;
    if (g < GG) {
#pragma unroll
        for (int k = 0; k < II; k++) wih[k] = W_ih[g * II + k];
#pragma unroll
        for (int j = 0; j < HH; j++) whh[j] = W_hh[g * HH + j];
        bias = b_ih[g] + b_hh[g];
    } else {
#pragma unroll
        for (int k = 0; k < II; k++) wih[k] = 0.f;
#pragma unroll
        for (int j = 0; j < HH; j++) whh[j] = 0.f;
    }

    // Unified activation: sigmoid for i,f,o; tanh for g (lanes 20..29).
    // sigmoid(z) = rcp(1 + exp2(-z*log2e)); tanh(z) = 2*sigmoid(2z) - 1.
    const float LOG2E = 1.4426950408889634f;
    const bool is_tanh = (g >= 2 * HH && g < 3 * HH);
    const float k1 = is_tanh ? (-2.f * LOG2E) : (-LOG2E);
    const float am = is_tanh ? 2.f : 1.f;
    const float ac = is_tanh ? -1.f : 0.f;

    // Recurrent state on lanes 0..9
    float hval = 0.f, cval = 0.f;
    if (lane < HH) {
        hval = h0[b * HH + lane];
        cval = c0[b * HH + lane];
    }

    const float* xrow = x + (size_t)b * TT * II;
    float* orow = out + (size_t)b * TT * HH;

    // src lane for the i/f/g/o gather (valid for all lanes, used by <10)
    const int j4 = (lane < HH) ? lane : 0;

#pragma unroll 4
    for (int t = 0; t < TT; t++) {
        // x_t is wave-uniform -> scalar-load friendly
        const float* xt = xrow + t * II;
        const float x0 = xt[0], x1 = xt[1], x2 = xt[2], x3 = xt[3], x4 = xt[4];

        // gate = bias + x.W_ih[g] + h.W_hh[g]
        float acc = bias;
        acc = fmaf(x0, wih[0], acc);
        acc = fmaf(x1, wih[1], acc);
        float acc2 = x2 * wih[2];
        acc2 = fmaf(x3, wih[3], acc2);
        acc2 = fmaf(x4, wih[4], acc2);

        // broadcast h[0..9] from lanes 0..9; two accumulators for ILP
#pragma unroll
        for (int j = 0; j < HH; j += 2) {
            const float hj0 = __shfl(hval, j, 64);
            const float hj1 = __shfl(hval, j + 1, 64);
            acc = fmaf(hj0, whh[j], acc);
            acc2 = fmaf(hj1, whh[j + 1], acc2);
        }
        acc += acc2;

        // activation (branchless sigmoid/tanh)
        const float e = __builtin_amdgcn_exp2f(acc * k1);
        const float s = __builtin_amdgcn_rcpf(1.f + e);
        const float act = fmaf(s, am, ac);

        // gather i,f,g,o for hidden unit j (lanes 0..9)
        const float iv = __shfl(act, j4, 64);
        const float fv = __shfl(act, j4 + HH, 64);
        const float gv = __shfl(act, j4 + 2 * HH, 64);
        const float ov = __shfl(act, j4 + 3 * HH, 64);

        // c' = f*c + i*g ; h' = o * tanh(c')
        cval = fmaf(fv, cval, iv * gv);
        const float e2 = __builtin_amdgcn_exp2f(cval * (-2.f * LOG2E));
        const float th = fmaf(__builtin_amdgcn_rcpf(1.f + e2), 2.f, -1.f);
        hval = ov * th;

        if (lane < HH) orow[t * HH + lane] = hval;
    }
}

extern "C" void kernel_launch(void* const* d_in, const int* in_sizes, int n_in,
                              void* d_out, int out_size, void* d_ws, size_t ws_size,
                              hipStream_t stream) {
    const float* x    = (const float*)d_in[0];
    const float* h0   = (const float*)d_in[1];
    const float* c0   = (const float*)d_in[2];
    const float* W_ih = (const float*)d_in[3];
    const float* W_hh = (const float*)d_in[4];
    const float* b_ih = (const float*)d_in[5];
    const float* b_hh = (const float*)d_in[6];
    float* out = (float*)d_out;

    lstm_wave_kernel<<<dim3(BB), dim3(64), 0, stream>>>(
        x, h0, c0, W_ih, W_hh, b_ih, b_hh, out);
}

// Round 2
// 1179.922 us; speedup vs baseline: 1.5653x; 1.5653x over previous
//
#include <hip/hip_runtime.h>

// LSTM: B=2048, T=4096, I=5, H=10, fp32. One wave per batch chain.
// Lane g<40 owns gate row g (order i,f,g,o). Lanes 0..9 own h[j], c[j].
// x is staged global->LDS in 256-step double-buffered chunks (float4 loads
// issued a full chunk ahead); per-step x reads are uniform ds_read broadcasts.
// h-broadcast uses v_readlane (constant lane idx, VALU not DS); f/g/o gather
// uses 3 ds_bpermute (i-gate is local on lanes 0..9).

#define BB 2048
#define TT 4096
#define II 5
#define HH 10
#define GG 40
#define CH 256                // timesteps per LDS chunk
#define CHF (CH * II)         // 1280 floats = 5120 B per buffer
#define NCHUNK (TT / CH)      // 16

__device__ __forceinline__ float readlane_f(float v, int l) {
    union { float f; int i; } u;
    u.f = v;
    u.i = __builtin_amdgcn_readlane(u.i, l);
    return u.f;
}

__global__ __launch_bounds__(64) void lstm_wave_kernel(
    const float* __restrict__ x,
    const float* __restrict__ h0,
    const float* __restrict__ c0,
    const float* __restrict__ W_ih,
    const float* __restrict__ W_hh,
    const float* __restrict__ b_ih,
    const float* __restrict__ b_hh,
    float* __restrict__ out)
{
    __shared__ float xs[2][CHF];   // 10 KiB / block; 8 blocks/CU -> 80 KiB

    const int b = blockIdx.x;
    const int lane = threadIdx.x;
    const int g = lane;

    // Per-lane gate-row weights
    float wih[II];
    float whh[HH];
    float bias = 0.f;
    if (g < GG) {
#pragma unroll
        for (int k = 0; k < II; k++) wih[k] = W_ih[g * II + k];
#pragma unroll
        for (int j = 0; j < HH; j++) whh[j] = W_hh[g * HH + j];
        bias = b_ih[g] + b_hh[g];
    } else {
#pragma unroll
        for (int k = 0; k < II; k++) wih[k] = 0.f;
#pragma unroll
        for (int j = 0; j < HH; j++) whh[j] = 0.f;
    }

    // sigmoid for i,f,o; tanh for g (lanes 20..29): tanh(z)=2*sigmoid(2z)-1
    const float LOG2E = 1.4426950408889634f;
    const bool is_tanh = (g >= 2 * HH && g < 3 * HH);
    const float k1 = is_tanh ? (-2.f * LOG2E) : (-LOG2E);
    const float am = is_tanh ? 2.f : 1.f;
    const float ac = is_tanh ? -1.f : 0.f;

    float hval = 0.f, cval = 0.f;
    if (lane < HH) {
        hval = h0[b * HH + lane];
        cval = c0[b * HH + lane];
    }

    const float* xrow = x + (size_t)b * TT * II;
    float* orow = out + (size_t)b * TT * HH;

    // ---- stage chunk 0 ----
    float4 pf0, pf1, pf2, pf3, pf4;
    {
        const float4* xv = (const float4*)xrow;
        pf0 = xv[0 * 64 + lane];
        pf1 = xv[1 * 64 + lane];
        pf2 = xv[2 * 64 + lane];
        pf3 = xv[3 * 64 + lane];
        pf4 = xv[4 * 64 + lane];
        float4* dst = (float4*)xs[0];
        dst[0 * 64 + lane] = pf0;
        dst[1 * 64 + lane] = pf1;
        dst[2 * 64 + lane] = pf2;
        dst[3 * 64 + lane] = pf3;
        dst[4 * 64 + lane] = pf4;
    }

    for (int c = 0; c < NCHUNK; ++c) {
        const float* xc = xs[c & 1];

        // issue next chunk's global loads now; consume ~256 steps later
        if (c + 1 < NCHUNK) {
            const float4* xv = (const float4*)(xrow + (size_t)(c + 1) * CHF);
            pf0 = xv[0 * 64 + lane];
            pf1 = xv[1 * 64 + lane];
            pf2 = xv[2 * 64 + lane];
            pf3 = xv[3 * 64 + lane];
            pf4 = xv[4 * 64 + lane];
        }

#pragma unroll 8
        for (int u = 0; u < CH; ++u) {
            const int t = c * CH + u;

            // x_t from LDS (uniform address -> broadcast, no conflicts)
            const float x0 = xc[u * II + 0];
            const float x1 = xc[u * II + 1];
            const float x2 = xc[u * II + 2];
            const float x3 = xc[u * II + 3];
            const float x4 = xc[u * II + 4];

            // gate preact: bias + x.W_ih[g] + h.W_hh[g], 4-acc tree
            float a0 = fmaf(x0, wih[0], bias);
            float a1 = x1 * wih[1];
            float a2 = x2 * wih[2];
            float a3 = x3 * wih[3];
            a0 = fmaf(x4, wih[4], a0);

            a1 = fmaf(readlane_f(hval, 0), whh[0], a1);
            a2 = fmaf(readlane_f(hval, 1), whh[1], a2);
            a3 = fmaf(readlane_f(hval, 2), whh[2], a3);
            a0 = fmaf(readlane_f(hval, 3), whh[3], a0);
            a1 = fmaf(readlane_f(hval, 4), whh[4], a1);
            a2 = fmaf(readlane_f(hval, 5), whh[5], a2);
            a3 = fmaf(readlane_f(hval, 6), whh[6], a3);
            a0 = fmaf(readlane_f(hval, 7), whh[7], a0);
            a1 = fmaf(readlane_f(hval, 8), whh[8], a1);
            a2 = fmaf(readlane_f(hval, 9), whh[9], a2);
            const float acc = (a0 + a1) + (a2 + a3);

            // branchless sigmoid/tanh
            const float e = __builtin_amdgcn_exp2f(acc * k1);
            const float s = __builtin_amdgcn_rcpf(1.f + e);
            const float act = fmaf(s, am, ac);

            // gather f,g,o (i is local: lanes 0..9 own gate rows 0..9)
            const float fv = __shfl(act, lane + HH, 64);
            const float gv = __shfl(act, lane + 2 * HH, 64);
            const float ov = __shfl(act, lane + 3 * HH, 64);

            cval = fmaf(fv, cval, act * gv);
            const float e2 = __builtin_amdgcn_exp2f(cval * (-2.f * LOG2E));
            const float th = fmaf(__builtin_amdgcn_rcpf(1.f + e2), 2.f, -1.f);
            hval = ov * th;

            if (lane < HH) orow[t * HH + lane] = hval;
        }

        // park the prefetched chunk into the other LDS buffer
        if (c + 1 < NCHUNK) {
            float4* dst = (float4*)xs[(c + 1) & 1];
            dst[0 * 64 + lane] = pf0;
            dst[1 * 64 + lane] = pf1;
            dst[2 * 64 + lane] = pf2;
            dst[3 * 64 + lane] = pf3;
            dst[4 * 64 + lane] = pf4;
        }
    }
}

extern "C" void kernel_launch(void* const* d_in, const int* in_sizes, int n_in,
                              void* d_out, int out_size, void* d_ws, size_t ws_size,
                              hipStream_t stream) {
    const float* x    = (const float*)d_in[0];
    const float* h0   = (const float*)d_in[1];
    const float* c0   = (const float*)d_in[2];
    const float* W_ih = (const float*)d_in[3];
    const float* W_hh = (const float*)d_in[4];
    const float* b_ih = (const float*)d_in[5];
    const float* b_hh = (const float*)d_in[6];
    float* out = (float*)d_out;

    lstm_wave_kernel<<<dim3(BB), dim3(64), 0, stream>>>(
        x, h0, c0, W_ih, W_hh, b_ih, b_hh, out);
}